// Round 5
// baseline (492.093 us; speedup 1.0000x reference)
//
#include <hip/hip_runtime.h>
#include <stdint.h>

#define DDIM 256
#define KCODES 1024
#define KDSZ (KCODES * DDIM)
#define ROWS 64
#define LDT 264     // fp16 LDS row stride (528 B): 2-way-only bank aliasing on frag reads
#define OUTOFF 16777216

typedef __attribute__((ext_vector_type(8))) _Float16 f16x8;
typedef __attribute__((ext_vector_type(4))) float f32x4;

__device__ inline unsigned short f2h(float f) {
  _Float16 h = (_Float16)f;
  return __builtin_bit_cast(unsigned short, h);
}

// ---- codebook prep: ch = fp16(-1024*cb), c2h = 512*||cb||^2; zero loss cells ----
// key = 512*c2 - 1024*S = 512*(c2 - 2S): same argmin order as reference distances.
__global__ __launch_bounds__(256) void k_prep(const float* __restrict__ cbs,
                                              _Float16* __restrict__ ch,
                                              float* __restrict__ c2h,
                                              float* __restrict__ out) {
  if (blockIdx.x == 0 && threadIdx.x == 0) {
    out[OUTOFF] = 0.f;
    out[OUTOFF + 1] = 0.f;
  }
  int code = blockIdx.x * 4 + (threadIdx.x >> 6);  // 0..3071 over [3][1024]
  int lane = threadIdx.x & 63;
  float4 v = ((const float4*)(cbs + (size_t)code * DDIM))[lane];
  ushort4 u;
  u.x = f2h(v.x * -1024.0f);
  u.y = f2h(v.y * -1024.0f);
  u.z = f2h(v.z * -1024.0f);
  u.w = f2h(v.w * -1024.0f);
  ((ushort4*)((unsigned short*)ch + (size_t)code * DDIM))[lane] = u;
  double s = (double)v.x * v.x + (double)v.y * v.y + (double)v.z * v.z + (double)v.w * v.w;
  for (int off = 1; off < 64; off <<= 1) s += __shfl_xor(s, off);
  if (lane == 0) c2h[code] = (float)(s * 512.0);
}

// ---- fused 3-stage RVQ: z home = fp16 LDS + global zcur; no register-resident z ----
// grid 1024 blocks x 256 threads; block owns 64 rows; waves split the 1024 codes 4-way.
__global__ __launch_bounds__(256, 2) void k_rvq(const float* __restrict__ z0,
                                                const float* __restrict__ cbs,
                                                const _Float16* __restrict__ ch,
                                                const float* __restrict__ c2h,
                                                float* __restrict__ zcur,
                                                float* __restrict__ outq) {
  __shared__ _Float16 s_z[ROWS * LDT];  // 33.8 KiB
  __shared__ float s_wv[4 * ROWS];
  __shared__ int s_wk[4 * ROWS];
  __shared__ int s_bk[ROWS];
  __shared__ float s_ls[4];

  const int tid = threadIdx.x;
  const int wid = tid >> 6;
  const int lane = tid & 63;
  const int l15 = lane & 15;
  const int lg = lane >> 4;  // 16-lane group 0..3
  const size_t gbase = (size_t)blockIdx.x * ROWS * DDIM;
  float lsum = 0.f;

  for (int s = 0; s < 3; ++s) {
    const float* zsrc = (s == 0) ? z0 : zcur;

    // ---- staging: global fp32 -> fp16 LDS (transient regs only) ----
#pragma unroll
    for (int it = 0; it < 16; ++it) {
      float4 v = *(const float4*)(zsrc + gbase + it * 1024 + tid * 4);
      ushort4 u;
      u.x = f2h(v.x); u.y = f2h(v.y); u.z = f2h(v.z); u.w = f2h(v.w);
      *(ushort4*)(&s_z[(it * 4 + wid) * LDT + lane * 4]) = u;
    }
    __syncthreads();

    // ---- gemm S^T = (-1024*cb) . z^T with acc init = 512*c2; running argmin ----
    const _Float16* chS = ch + (size_t)s * KDSZ;
    const float* c2S = c2h + s * KCODES;
    float bv[4];
    int bk[4];
#pragma unroll
    for (int i = 0; i < 4; ++i) { bv[i] = 3.4e38f; bk[i] = 0x3FFFFFFF; }

    const int code00 = wid * 256;  // each wave owns 256 consecutive codes
    for (int cb2 = 0; cb2 < 4; ++cb2) {
      const int codeB = code00 + cb2 * 64;
      f32x4 acc[4][4];
#pragma unroll
      for (int j = 0; j < 4; ++j) {
        float4 ci = *(const float4*)(c2S + codeB + j * 16 + lg * 4);
        f32x4 cv = {ci.x, ci.y, ci.z, ci.w};
#pragma unroll
        for (int i = 0; i < 4; ++i) acc[i][j] = cv;
      }
#pragma unroll
      for (int kc = 0; kc < 8; ++kc) {
        f16x8 a[4], b[4];
#pragma unroll
        for (int j = 0; j < 4; ++j)
          a[j] = *(const f16x8*)(chS + (size_t)(codeB + j * 16 + l15) * DDIM + kc * 32 + lg * 8);
#pragma unroll
        for (int i = 0; i < 4; ++i)
          b[i] = *(const f16x8*)(&s_z[(i * 16 + l15) * LDT + kc * 32 + lg * 8]);
#pragma unroll
        for (int i = 0; i < 4; ++i)
#pragma unroll
          for (int j = 0; j < 4; ++j)
            acc[i][j] = __builtin_amdgcn_mfma_f32_16x16x32_f16(a[j], b[i], acc[i][j], 0, 0, 0);
      }
      // lane-local running argmin; traversal (cb2, j, r) ascending -> strict < = first-min
#pragma unroll
      for (int j = 0; j < 4; ++j) {
#pragma unroll
        for (int r = 0; r < 4; ++r) {
          int kcode = codeB + j * 16 + lg * 4 + r;
#pragma unroll
          for (int i = 0; i < 4; ++i) {
            float v = acc[i][j][r];
            if (v < bv[i]) { bv[i] = v; bk[i] = kcode; }
          }
        }
      }
    }

    // reduce across the 4 lane-groups (codes split by lg), tie-break lower index
#pragma unroll
    for (int m = 16; m <= 32; m <<= 1) {
#pragma unroll
      for (int i = 0; i < 4; ++i) {
        float ov = __shfl_xor(bv[i], m);
        int ok = __shfl_xor(bk[i], m);
        if (ov < bv[i] || (ov == bv[i] && ok < bk[i])) { bv[i] = ov; bk[i] = ok; }
      }
    }
    if (lane < 16) {
#pragma unroll
      for (int i = 0; i < 4; ++i) {
        s_wv[wid * ROWS + i * 16 + lane] = bv[i];
        s_wk[wid * ROWS + i * 16 + lane] = bk[i];
      }
    }
    __syncthreads();
    if (tid < ROWS) {  // min over the 4 waves' code-slices per zrow
      float v = s_wv[tid];
      int k = s_wk[tid];
#pragma unroll
      for (int w = 1; w < 4; ++w) {
        float vv = s_wv[w * ROWS + tid];
        int kk = s_wk[w * ROWS + tid];
        if (vv < v || (vv == v && kk < k)) { v = vv; k = kk; }
      }
      s_bk[tid] = k;
    }
    __syncthreads();

    // ---- epilogue: gather + losses + residual update (exact fp32 reference rounding) ----
    float lacc = 0.f;
    const float* cbsS = cbs + (size_t)s * KDSZ;
#pragma unroll
    for (int it = 0; it < 16; ++it) {
      int row = it * 4 + wid;
      int code = s_bk[row];
      float4 zv = *(const float4*)(zsrc + gbase + it * 1024 + tid * 4);  // L2/L3-hot
      float4 cv = *(const float4*)(cbsS + (size_t)code * DDIM + lane * 4);
      float tx = cv.x - zv.x, ty = cv.y - zv.y, tz = cv.z - zv.z, tw = cv.w - zv.w;
      lacc += (tx * tx + ty * ty) + (tz * tz + tw * tw);
      float cstx = zv.x + tx, csty = zv.y + ty, cstz = zv.z + tz, cstw = zv.w + tw;
      float znx = zv.x - cstx, zny = zv.y - csty, znz = zv.z - cstz, znw = zv.w - cstw;
      if (s < 2) {
        float4 o; o.x = znx; o.y = zny; o.z = znz; o.w = znw;
        *(float4*)(zcur + gbase + it * 1024 + tid * 4) = o;  // same thread, same addr next stage
      } else {
        float4 a = *(const float4*)(z0 + gbase + it * 1024 + tid * 4);
        float4 o;
        o.x = a.x - znx; o.y = a.y - zny; o.z = a.z - znz; o.w = a.w - znw;
        *(float4*)(outq + gbase + it * 1024 + tid * 4) = o;  // out = z0 - z3
      }
    }
    for (int m = 1; m < 64; m <<= 1) lacc += __shfl_xor(lacc, m);
    if (lane == 0) s_ls[wid] = lacc;
    __syncthreads();
    if (tid == 0) lsum += (s_ls[0] + s_ls[1]) + (s_ls[2] + s_ls[3]);
    __syncthreads();  // s_ls consumed; s_z/s_wv/s_bk free for next stage
  }

  if (tid == 0) {
    float v = lsum * (1.0f / 16777216.0f);
    atomicAdd(outq + OUTOFF, v);      // codebook_loss
    atomicAdd(outq + OUTOFF + 1, v);  // commitment_loss (equal in forward)
  }
}

extern "C" void kernel_launch(void* const* d_in, const int* in_sizes, int n_in,
                              void* d_out, int out_size, void* d_ws, size_t ws_size,
                              hipStream_t stream) {
  const float* z0 = (const float*)d_in[0];
  const float* cbs = (const float*)d_in[1];
  float* out = (float*)d_out;
  char* ws = (char*)d_ws;
  float* zcur = (float*)ws;                  // 64 MB
  _Float16* ch = (_Float16*)(ws + 67108864); // 1.5 MB
  float* c2h = (float*)(ws + 68681728);      // 12 KB

  k_prep<<<768, 256, 0, stream>>>(cbs, ch, c2h, out);
  k_rvq<<<1024, 256, 0, stream>>>(z0, cbs, ch, c2h, zcur, out);
}

// Round 6
// 382.833 us; speedup vs baseline: 1.2854x; 1.2854x over previous
//
#include <hip/hip_runtime.h>
#include <stdint.h>

#define DDIM 256
#define KCODES 1024
#define OUTOFF 16777216
#define ZT 131072  // z-tile byte offset within LDS

typedef __attribute__((ext_vector_type(8))) _Float16 f16x8;
typedef __attribute__((ext_vector_type(4))) float f32x4;

__device__ inline void gld16(const void* g, void* l) {
  __builtin_amdgcn_global_load_lds(
      (const __attribute__((address_space(1))) unsigned int*)g,
      (__attribute__((address_space(3))) unsigned int*)l, 16, 0, 0);
}

// ---- codebook prep: fp16(-1024*cb) in SWIZZLED 16-code slabs + c2h = 512*||cb||^2 ----
// key = 512*c2 - 1024*S = 512*(c2 - 2S): same argmin order as reference distances.
// slab layout byte: (code>>4)*8192 + (code&15)*512 + ((g ^ (((code&15)&7)<<2))<<4), g = dim granule (8 elems)
__global__ __launch_bounds__(256) void k_prep(const float* __restrict__ cbs,
                                              unsigned short* __restrict__ ch,
                                              float* __restrict__ c2h,
                                              float* __restrict__ out) {
  if (blockIdx.x == 0 && threadIdx.x == 0) { out[OUTOFF] = 0.f; out[OUTOFF + 1] = 0.f; }
  int code = blockIdx.x * 4 + (threadIdx.x >> 6);  // 0..3071 over [3][1024]
  int lane = threadIdx.x & 63;
  float4 v = ((const float4*)(cbs + (size_t)code * DDIM))[lane];
  ushort4 u;
  u.x = __builtin_bit_cast(unsigned short, (_Float16)(v.x * -1024.0f));
  u.y = __builtin_bit_cast(unsigned short, (_Float16)(v.y * -1024.0f));
  u.z = __builtin_bit_cast(unsigned short, (_Float16)(v.z * -1024.0f));
  u.w = __builtin_bit_cast(unsigned short, (_Float16)(v.w * -1024.0f));
  int r = code & 15;
  int g = lane >> 1;  // granule (8 dims); lane covers half of it
  size_t byteoff = (size_t)(code >> 4) * 8192 + (size_t)r * 512 +
                   (size_t)((g ^ ((r & 7) << 2)) << 4) + (size_t)(lane & 1) * 8;
  *(ushort4*)((char*)ch + byteoff) = u;
  double s = (double)v.x * v.x + (double)v.y * v.y + (double)v.z * v.z + (double)v.w * v.w;
  for (int off = 1; off < 64; off <<= 1) s += __shfl_xor(s, off);
  if (lane == 0) c2h[code] = (float)(s * 512.0);
}

// ---- fused 3-stage RVQ: z fp32 in regs, z fp16 frags in regs, codebook via async
// gld_lds dbuf slabs. 1024 blocks x 512 threads (8 waves); block owns 64 rows;
// waves split 1024 codes 8-way (128 codes each, 8 chunks of 16).
// LDS: A-slabs 8w x 2 x 8192 @0 (131072) + z-tile 64x512B swizzled @131072 = 163840.
// argmin scratch aliases wave7-slot1 (122880..127264), dead between (C0) and next prefetch.
__global__ __launch_bounds__(512, 2) void k_rvq(const float* __restrict__ z0,
                                                const float* __restrict__ cbs,
                                                const unsigned short* __restrict__ ch,
                                                const float* __restrict__ c2h,
                                                float* __restrict__ outq) {
  __shared__ char lds[163840];
  float* s_wv8 = (float*)(lds + 122880);  // [8][64]
  int* s_wk8 = (int*)(lds + 124928);      // [8][64]
  int* s_bk = (int*)(lds + 126976);       // [64]
  float* s_ls = (float*)(lds + 127232);   // [8]

  const int tid = threadIdx.x;
  const int w = tid >> 6;
  const int lane = tid & 63;
  const int l15 = lane & 15;
  const int lg = lane >> 4;
  const int erow = w * 8 + (lane & 7);  // epilogue row (row-split across waves)
  const int ecb = lane >> 3;            // epilogue col-block: cols ecb*32..+32
  const size_t gbase = (size_t)blockIdx.x * 64 * DDIM;
  const size_t elane = gbase + (size_t)erow * DDIM + ecb * 32;
  char* myslab = lds + w * 16384;

  // z0 -> fp32 regs (persistent residual)
  float4 f[8];
#pragma unroll
  for (int q = 0; q < 8; ++q) f[q] = *(const float4*)(z0 + elane + q * 4);

  float lsum = 0.f;

  for (int s = 0; s < 3; ++s) {
    // ---- staging: fp32 regs -> swizzled fp16 z-tile ----
#pragma unroll
    for (int g2 = 0; g2 < 4; ++g2) {
      float4 va = f[2 * g2], vb = f[2 * g2 + 1];
      f16x8 hv;
      hv[0] = (_Float16)va.x; hv[1] = (_Float16)va.y; hv[2] = (_Float16)va.z; hv[3] = (_Float16)va.w;
      hv[4] = (_Float16)vb.x; hv[5] = (_Float16)vb.y; hv[6] = (_Float16)vb.z; hv[7] = (_Float16)vb.w;
      int g = ecb * 4 + g2;
      *(f16x8*)(lds + ZT + erow * 512 + ((g ^ ((erow & 7) << 2)) << 4)) = hv;
    }
    __syncthreads();  // (B) z-tile ready

    // ---- B-frags: whole 64-row fp16 slice -> registers (once per stage) ----
    f16x8 b[4][8];
#pragma unroll
    for (int i = 0; i < 4; ++i)
#pragma unroll
      for (int kc = 0; kc < 8; ++kc) {
        int row = i * 16 + l15;
        int g = kc * 4 + lg;
        b[i][kc] = *(const f16x8*)(lds + ZT + row * 512 + ((g ^ ((row & 7) << 2)) << 4));
      }

    const char* chS = (const char*)ch + (size_t)s * 524288;
    const float* c2S = c2h + s * KCODES;
    float bv[4];
    int bk[4];
#pragma unroll
    for (int i = 0; i < 4; ++i) { bv[i] = 3.4e38f; bk[i] = 0x3FFFFFFF; }

    // prologue: slab 0 + c2_0
    float4 c2cur = *(const float4*)(c2S + w * 128 + lg * 4);
    {
      const char* src = chS + (size_t)w * 8 * 8192;
#pragma unroll
      for (int i = 0; i < 8; ++i)
        gld16(src + lane * 16 + i * 1024, myslab + lane * 16 + i * 1024);
    }

    // ---- chunk loop: barrier-free, wave-local counted vmcnt pipeline ----
    for (int c = 0; c < 8; ++c) {
      float4 c2next;
      if (c < 7) {
        c2next = *(const float4*)(c2S + w * 128 + (c + 1) * 16 + lg * 4);
        const char* src = chS + (size_t)(w * 8 + c + 1) * 8192;
        char* dst = myslab + ((c + 1) & 1) * 8192;
#pragma unroll
        for (int i = 0; i < 8; ++i)
          gld16(src + lane * 16 + i * 1024, dst + lane * 16 + i * 1024);
        asm volatile("s_waitcnt vmcnt(9)" ::: "memory");  // slab c complete (9 newer ops in flight)
      } else {
        asm volatile("s_waitcnt vmcnt(0)" ::: "memory");
      }
      __builtin_amdgcn_sched_barrier(0);

      f32x4 acc[4];
      f32x4 cv = {c2cur.x, c2cur.y, c2cur.z, c2cur.w};
#pragma unroll
      for (int i = 0; i < 4; ++i) acc[i] = cv;  // acc init = 512*c2 (R5-identical rounding)
      const char* slab = myslab + (c & 1) * 8192;
#pragma unroll
      for (int kc = 0; kc < 8; ++kc) {
        f16x8 a = *(const f16x8*)(slab + l15 * 512 + (((kc * 4 + lg) ^ ((l15 & 7) << 2)) << 4));
#pragma unroll
        for (int i = 0; i < 4; ++i)
          acc[i] = __builtin_amdgcn_mfma_f32_16x16x32_f16(a, b[i][kc], acc[i], 0, 0, 0);
      }
      // running argmin; traversal (c, r) ascending -> strict < = first-min
#pragma unroll
      for (int r = 0; r < 4; ++r) {
        int kcode = w * 128 + c * 16 + lg * 4 + r;
#pragma unroll
        for (int i = 0; i < 4; ++i) {
          float v = acc[i][r];
          if (v < bv[i]) { bv[i] = v; bk[i] = kcode; }
        }
      }
      if (c < 7) c2cur = c2next;
    }
    __syncthreads();  // (C0) all slab reads done -> scratch region reusable

    // reduce across lane-groups (codes), tie-break lower index
#pragma unroll
    for (int m = 16; m <= 32; m <<= 1)
#pragma unroll
      for (int i = 0; i < 4; ++i) {
        float ov = __shfl_xor(bv[i], m);
        int ok = __shfl_xor(bk[i], m);
        if (ov < bv[i] || (ov == bv[i] && ok < bk[i])) { bv[i] = ov; bk[i] = ok; }
      }
    if (lane < 16)
#pragma unroll
      for (int i = 0; i < 4; ++i) {
        s_wv8[w * 64 + i * 16 + lane] = bv[i];
        s_wk8[w * 64 + i * 16 + lane] = bk[i];
      }
    __syncthreads();  // (C)
    if (tid < 64) {  // min over 8 waves' code-slices per row (wave index ascends with code)
      float v = s_wv8[tid];
      int k = s_wk8[tid];
#pragma unroll
      for (int w2 = 1; w2 < 8; ++w2) {
        float vv = s_wv8[w2 * 64 + tid];
        int kk = s_wk8[w2 * 64 + tid];
        if (vv < v || (vv == v && kk < k)) { v = vv; k = kk; }
      }
      s_bk[tid] = k;
    }
    __syncthreads();  // (D)

    // ---- epilogue: gather + loss + residual in regs (exact fp32 reference rounding) ----
    float lacc = 0.f;
    {
      const float* cbsS = cbs + (size_t)s * (KCODES * DDIM);
      int code = s_bk[erow];
      const float* cp = cbsS + (size_t)code * DDIM + ecb * 32;
#pragma unroll
      for (int q = 0; q < 8; ++q) {
        float4 cv2 = *(const float4*)(cp + q * 4);
        float4 zv = f[q];
        float tx = cv2.x - zv.x, ty = cv2.y - zv.y, tz = cv2.z - zv.z, tw = cv2.w - zv.w;
        lacc += (tx * tx + ty * ty) + (tz * tz + tw * tw);
        float cstx = zv.x + tx, csty = zv.y + ty, cstz = zv.z + tz, cstw = zv.w + tw;
        float znx = zv.x - cstx, zny = zv.y - csty, znz = zv.z - cstz, znw = zv.w - cstw;
        if (s < 2) {
          f[q].x = znx; f[q].y = zny; f[q].z = znz; f[q].w = znw;
        } else {
          float4 a = *(const float4*)(z0 + elane + q * 4);
          float4 o;
          o.x = a.x - znx; o.y = a.y - zny; o.z = a.z - znz; o.w = a.w - znw;
          *(float4*)(outq + elane + q * 4) = o;  // out = z0 - z3
        }
      }
    }
#pragma unroll
    for (int m = 1; m < 64; m <<= 1) lacc += __shfl_xor(lacc, m);
    if (lane == 0) s_ls[w] = lacc;
    __syncthreads();  // (E)
    if (tid == 0)
      lsum += ((s_ls[0] + s_ls[1]) + (s_ls[2] + s_ls[3])) +
              ((s_ls[4] + s_ls[5]) + (s_ls[6] + s_ls[7]));
    // next stage's staging/(B) orders the scratch reads vs wave7-slot1 prefetch
  }

  if (tid == 0) {
    float v = lsum * (1.0f / 16777216.0f);
    atomicAdd(outq + OUTOFF, v);      // codebook_loss
    atomicAdd(outq + OUTOFF + 1, v);  // commitment_loss (equal in forward)
  }
}

extern "C" void kernel_launch(void* const* d_in, const int* in_sizes, int n_in,
                              void* d_out, int out_size, void* d_ws, size_t ws_size,
                              hipStream_t stream) {
  const float* z0 = (const float*)d_in[0];
  const float* cbs = (const float*)d_in[1];
  float* out = (float*)d_out;
  char* ws = (char*)d_ws;
  unsigned short* ch = (unsigned short*)ws;  // 1.5 MB swizzled fp16 slabs
  float* c2h = (float*)(ws + 1572864);       // 12 KB

  k_prep<<<768, 256, 0, stream>>>(cbs, ch, c2h, out);
  k_rvq<<<1024, 512, 0, stream>>>(z0, cbs, ch, c2h, out);
}

// Round 7
// 366.596 us; speedup vs baseline: 1.3423x; 1.0443x over previous
//
#include <hip/hip_runtime.h>
#include <stdint.h>

#define DDIM 256
#define KCODES 1024
#define OUTOFF 16777216
#define HT 131072  // hi-tile byte offset in LDS

typedef __attribute__((ext_vector_type(8))) _Float16 f16x8;
typedef __attribute__((ext_vector_type(4))) float f32x4;

__device__ inline void gld16(const void* g, void* l) {
  __builtin_amdgcn_global_load_lds(
      (const __attribute__((address_space(1))) unsigned int*)g,
      (__attribute__((address_space(3))) unsigned int*)l, 16, 0, 0);
}

// ---- codebook prep: fp16(-1024*cb) in swizzled 16-code slabs + c2h = 512*||cb||^2 ----
// key = 512*c2 - 1024*S = 512*(c2 - 2S): same argmin order as reference distances.
// slab byte: (code>>4)*8192 + (code&15)*512 + ((g ^ (r&7))<<4), g = dim-granule (8 elems), r = code&15.
// slot = g ^ (r&7): bank-quad = (g%8)^(r&7) -> uniform 8 lanes/quad on all hot reads.
__global__ __launch_bounds__(256) void k_prep(const float* __restrict__ cbs,
                                              unsigned short* __restrict__ ch,
                                              float* __restrict__ c2h,
                                              float* __restrict__ out) {
  if (blockIdx.x == 0 && threadIdx.x == 0) { out[OUTOFF] = 0.f; out[OUTOFF + 1] = 0.f; }
  int code = blockIdx.x * 4 + (threadIdx.x >> 6);  // 0..3071 over [3][1024]
  int lane = threadIdx.x & 63;
  float4 v = ((const float4*)(cbs + (size_t)code * DDIM))[lane];
  ushort4 u;
  u.x = __builtin_bit_cast(unsigned short, (_Float16)(v.x * -1024.0f));
  u.y = __builtin_bit_cast(unsigned short, (_Float16)(v.y * -1024.0f));
  u.z = __builtin_bit_cast(unsigned short, (_Float16)(v.z * -1024.0f));
  u.w = __builtin_bit_cast(unsigned short, (_Float16)(v.w * -1024.0f));
  int r = code & 15;
  int g = lane >> 1;
  size_t byteoff = (size_t)(code >> 4) * 8192 + (size_t)r * 512 +
                   (size_t)((g ^ (r & 7)) << 4) + (size_t)(lane & 1) * 8;
  *(ushort4*)((char*)ch + byteoff) = u;
  double s = (double)v.x * v.x + (double)v.y * v.y + (double)v.z * v.z + (double)v.w * v.w;
  for (int off = 1; off < 64; off <<= 1) s += __shfl_xor(s, off);
  if (lane == 0) c2h[code] = (float)(s * 512.0);
}

// ---- fused 3-stage RVQ. z identity = hi(fp16 LDS tile, updated in place) + lo(16 VGPRs).
// 1024 blocks x 512 threads (8 waves); block owns 64 rows; waves split 1024 codes 8-way.
// LDS 160 KB exactly: A-slabs 8w x 2 x 8192 @0 (131072) + hi tile 64x512B @131072.
// argmin scratch aliases wave7-slot1 (122880..127264): all scratch use sits between the
// (C0) barrier (slab reads done) and the next slot1 prefetch (chunk-0 of next stage,
// which is after the (B) barrier that follows every s_bk read). s_ls used only at kernel end.
__global__ __launch_bounds__(512)
__attribute__((amdgpu_waves_per_eu(2, 2)))
void k_rvq(const float* __restrict__ z0,
           const float* __restrict__ cbs,
           const unsigned short* __restrict__ ch,
           const float* __restrict__ c2h,
           float* __restrict__ outq) {
  __shared__ char lds[163840];
  float* s_wv8 = (float*)(lds + 122880);  // [8][64]
  int* s_wk8 = (int*)(lds + 124928);      // [8][64]
  int* s_bk = (int*)(lds + 126976);       // [64]
  float* s_ls = (float*)(lds + 127232);   // [8] (kernel-end only)

  const int tid = threadIdx.x;
  const int w = tid >> 6;
  const int lane = tid & 63;
  const int l15 = lane & 15;
  const int lg = lane >> 4;
  const int erow = w * 8 + (lane & 7);  // epilogue row
  const int ecb = lane >> 3;            // epilogue col-block: cols ecb*32..+32
  const size_t gbase = (size_t)blockIdx.x * 64 * DDIM;
  const size_t ebase = gbase + (size_t)erow * DDIM + ecb * 32;
  char* myslab = lds + w * 16384;
  char* hirow = lds + HT + erow * 512;

  // ---- initial staging: z0 -> hi tile (LDS) + lo residual (regs) ----
  f16x8 lo[4];
#pragma unroll
  for (int q = 0; q < 4; ++q) {
    float4 va = *(const float4*)(z0 + ebase + q * 8);
    float4 vb = *(const float4*)(z0 + ebase + q * 8 + 4);
    f16x8 hv, lv;
    hv[0] = (_Float16)va.x; hv[1] = (_Float16)va.y; hv[2] = (_Float16)va.z; hv[3] = (_Float16)va.w;
    hv[4] = (_Float16)vb.x; hv[5] = (_Float16)vb.y; hv[6] = (_Float16)vb.z; hv[7] = (_Float16)vb.w;
    lv[0] = (_Float16)(va.x - (float)hv[0]); lv[1] = (_Float16)(va.y - (float)hv[1]);
    lv[2] = (_Float16)(va.z - (float)hv[2]); lv[3] = (_Float16)(va.w - (float)hv[3]);
    lv[4] = (_Float16)(vb.x - (float)hv[4]); lv[5] = (_Float16)(vb.y - (float)hv[5]);
    lv[6] = (_Float16)(vb.z - (float)hv[6]); lv[7] = (_Float16)(vb.w - (float)hv[7]);
    *(f16x8*)(hirow + (((ecb * 4 + q) ^ (erow & 7)) << 4)) = hv;
    lo[q] = lv;
  }

  float wloss = 0.f;

  for (int s = 0; s < 3; ++s) {
    __syncthreads();  // (B) hi tile ready (staging or previous epilogue writes)

    // ---- b-frags: whole 64-row hi slice -> 128 VGPRs (once per stage) ----
    f16x8 b[4][8];
#pragma unroll
    for (int i = 0; i < 4; ++i)
#pragma unroll
      for (int kc = 0; kc < 8; ++kc)
        b[i][kc] = *(const f16x8*)(lds + HT + (i * 16 + l15) * 512 +
                                   (((kc * 4 + lg) ^ (l15 & 7)) << 4));

    const char* chS = (const char*)ch + (size_t)s * 524288;
    const float* c2S = c2h + s * KCODES;
    float bv[4];
    int bk[4];
#pragma unroll
    for (int i = 0; i < 4; ++i) { bv[i] = 3.4e38f; bk[i] = 0x3FFFFFFF; }

    // prologue: c2_0 + slab 0
    float4 c2cur = *(const float4*)(c2S + w * 128 + lg * 4);
    {
      const char* src = chS + (size_t)w * 8 * 8192;
#pragma unroll
      for (int i = 0; i < 8; ++i)
        gld16(src + lane * 16 + i * 1024, myslab + lane * 16 + i * 1024);
    }

    // ---- chunk loop: barrier-free, wave-local counted vmcnt pipeline ----
    for (int c = 0; c < 8; ++c) {
      float4 c2next;
      if (c < 7) {
        c2next = *(const float4*)(c2S + w * 128 + (c + 1) * 16 + lg * 4);
        const char* src = chS + (size_t)(w * 8 + c + 1) * 8192;
        char* dst = myslab + ((c + 1) & 1) * 8192;
#pragma unroll
        for (int i = 0; i < 8; ++i)
          gld16(src + lane * 16 + i * 1024, dst + lane * 16 + i * 1024);
        asm volatile("s_waitcnt vmcnt(9)" ::: "memory");  // slab c complete (9 newer in flight)
      } else {
        asm volatile("s_waitcnt vmcnt(0)" ::: "memory");
      }
      __builtin_amdgcn_sched_barrier(0);

      f32x4 acc[4];
      f32x4 cv = {c2cur.x, c2cur.y, c2cur.z, c2cur.w};
#pragma unroll
      for (int i = 0; i < 4; ++i) acc[i] = cv;  // acc init = 512*c2
      const char* slab = myslab + (c & 1) * 8192;
#pragma unroll
      for (int kc = 0; kc < 8; ++kc) {
        f16x8 a = *(const f16x8*)(slab + l15 * 512 + (((kc * 4 + lg) ^ (l15 & 7)) << 4));
#pragma unroll
        for (int i = 0; i < 4; ++i)
          acc[i] = __builtin_amdgcn_mfma_f32_16x16x32_f16(a, b[i][kc], acc[i], 0, 0, 0);
      }
      // running argmin; traversal (c, r) ascending per lane -> strict < = first-min
#pragma unroll
      for (int r = 0; r < 4; ++r) {
        int kcode = w * 128 + c * 16 + lg * 4 + r;
#pragma unroll
        for (int i = 0; i < 4; ++i) {
          float v = acc[i][r];
          if (v < bv[i]) { bv[i] = v; bk[i] = kcode; }
        }
      }
      if (c < 7) c2cur = c2next;
    }
    __syncthreads();  // (C0) all slab reads done -> scratch region reusable

    // reduce across lane-groups (codes), tie-break lower index
#pragma unroll
    for (int m = 16; m <= 32; m <<= 1)
#pragma unroll
      for (int i = 0; i < 4; ++i) {
        float ov = __shfl_xor(bv[i], m);
        int ok = __shfl_xor(bk[i], m);
        if (ov < bv[i] || (ov == bv[i] && ok < bk[i])) { bv[i] = ov; bk[i] = ok; }
      }
    if (lane < 16)
#pragma unroll
      for (int i = 0; i < 4; ++i) {
        s_wv8[w * 64 + i * 16 + lane] = bv[i];
        s_wk8[w * 64 + i * 16 + lane] = bk[i];
      }
    __syncthreads();  // (C)
    if (tid < 64) {  // min over 8 waves' code-slices per row
      float v = s_wv8[tid];
      int k = s_wk8[tid];
#pragma unroll
      for (int w2 = 1; w2 < 8; ++w2) {
        float vv = s_wv8[w2 * 64 + tid];
        int kk = s_wk8[w2 * 64 + tid];
        if (vv < v || (vv == v && kk < k)) { v = vv; k = kk; }
      }
      s_bk[tid] = k;
    }
    __syncthreads();  // (D)

    // ---- epilogue: gather + loss + residual; hi tile updated IN PLACE, lo in regs ----
    float lacc = 0.f;
    {
      int code = s_bk[erow];
      const float* cp = cbs + (size_t)s * (KCODES * DDIM) + (size_t)code * DDIM + ecb * 32;
#pragma unroll
      for (int q = 0; q < 4; ++q) {
        int slot = ((ecb * 4 + q) ^ (erow & 7)) << 4;
        f16x8 hv = *(const f16x8*)(hirow + slot);
        float zz[8], cc[8], zn[8];
#pragma unroll
        for (int k2 = 0; k2 < 8; ++k2) zz[k2] = (float)hv[k2] + (float)lo[q][k2];
        float4 c0 = *(const float4*)(cp + q * 8);
        float4 c1 = *(const float4*)(cp + q * 8 + 4);
        cc[0] = c0.x; cc[1] = c0.y; cc[2] = c0.z; cc[3] = c0.w;
        cc[4] = c1.x; cc[5] = c1.y; cc[6] = c1.z; cc[7] = c1.w;
#pragma unroll
        for (int k2 = 0; k2 < 8; ++k2) {
          float t = cc[k2] - zz[k2];
          lacc += t * t;
          float cst = zz[k2] + t;     // codes_st (reference rounding)
          zn[k2] = zz[k2] - cst;      // next residual
        }
        if (s < 2) {
          f16x8 nh, nl;
#pragma unroll
          for (int k2 = 0; k2 < 8; ++k2) {
            nh[k2] = (_Float16)zn[k2];
            nl[k2] = (_Float16)(zn[k2] - (float)nh[k2]);
          }
          *(f16x8*)(hirow + slot) = nh;
          lo[q] = nl;
        } else {
          float4 a0 = *(const float4*)(z0 + ebase + q * 8);
          float4 a1 = *(const float4*)(z0 + ebase + q * 8 + 4);
          float4 o0, o1;
          o0.x = a0.x - zn[0]; o0.y = a0.y - zn[1]; o0.z = a0.z - zn[2]; o0.w = a0.w - zn[3];
          o1.x = a1.x - zn[4]; o1.y = a1.y - zn[5]; o1.z = a1.z - zn[6]; o1.w = a1.w - zn[7];
          *(float4*)(outq + ebase + q * 8) = o0;      // out = z0 - z3
          *(float4*)(outq + ebase + q * 8 + 4) = o1;
        }
      }
    }
#pragma unroll
    for (int m = 1; m < 64; m <<= 1) lacc += __shfl_xor(lacc, m);
    wloss += lacc;  // same value on all lanes; lane 0 used at end
    // next stage's (B) barrier orders hi-tile writes before b-loads, and s_bk reads
    // (done above) before the next slot1 prefetch.
  }

  // ---- kernel-end loss: slabs dead forever, scratch safe ----
  if (lane == 0) s_ls[w] = wloss;
  __syncthreads();
  if (tid == 0) {
    float t = ((s_ls[0] + s_ls[1]) + (s_ls[2] + s_ls[3])) +
              ((s_ls[4] + s_ls[5]) + (s_ls[6] + s_ls[7]));
    float v = t * (1.0f / 16777216.0f);
    atomicAdd(outq + OUTOFF, v);      // codebook_loss
    atomicAdd(outq + OUTOFF + 1, v);  // commitment_loss (equal in forward)
  }
}

extern "C" void kernel_launch(void* const* d_in, const int* in_sizes, int n_in,
                              void* d_out, int out_size, void* d_ws, size_t ws_size,
                              hipStream_t stream) {
  const float* z0 = (const float*)d_in[0];
  const float* cbs = (const float*)d_in[1];
  float* out = (float*)d_out;
  char* ws = (char*)d_ws;
  unsigned short* ch = (unsigned short*)ws;  // 1.5 MB swizzled fp16 slabs
  float* c2h = (float*)(ws + 1572864);       // 12 KB

  k_prep<<<768, 256, 0, stream>>>(cbs, ch, c2h, out);
  k_rvq<<<1024, 512, 0, stream>>>(z0, cbs, ch, c2h, out);
}